// Round 4
// baseline (553.650 us; speedup 1.0000x reference)
//
#include <hip/hip_runtime.h>
#include <hip/hip_bf16.h>
#include <math.h>

#define N 8192
#define NEGV -1000000000.0f
#define EPSV 1e-05f
#define NSPLIT 8
#define CPS (N / NSPLIT)   // 1024 columns per split
#define NTILE (CPS / 64)   // 16 tiles

typedef short bf16x8 __attribute__((ext_vector_type(8)));
typedef float f32x4 __attribute__((ext_vector_type(4)));
typedef unsigned short u16;

// ---- float workspace layout ----
#define WS_SCAL 0
#define WS_H    64                        // N*64 fp32
#define WS_ST   (WS_H + N * 64)           // N
#define WS_SBI  (WS_ST + N)               // N
#define WS_DEN  (WS_SBI + N)              // NSPLIT*N
#define WS_AGG  (WS_DEN + NSPLIT * N)     // NSPLIT*N*64
#define WS_F_END (WS_AGG + NSPLIT * N * 64)
// ---- u16 (bf16) region, offsets in u16 units from (u16*)ws ----
#define WU_BASE (WS_F_END * 2)
#define WU_QB (WU_BASE)                   // N*64
#define WU_KB (WU_BASE + N * 64)          // N*64
#define WU_MB (WU_BASE + 2 * N * 64)      // N*64 (row-major, transposed later)
#define WU_MT (WU_BASE + 3 * N * 64)      // 64*N

static __device__ __forceinline__ u16 f2bf(float f) {
    __hip_bfloat16 h = __float2bfloat16(f);
    return *(u16*)&h;
}

// ---------------- Kernel A: scalar prep ----------------
__global__ void prep_k(const float* __restrict__ tc, const float* __restrict__ wg,
                       const float* __restrict__ bg, const float* __restrict__ sbias,
                       float* __restrict__ scal) {
    int j = threadIdx.x;  // 64 threads
    float v = tc[0] * wg[j] + tc[1] * wg[64 + j] + bg[j];
    float g = 1.0f / (1.0f + __expf(-v));
    for (int off = 32; off; off >>= 1) g += __shfl_xor(g, off, 64);
    if (j == 0) {
        scal[0] = 0.125f * (g * (1.0f / 64.0f));   // qscale (gate mean + 1/sqrt(64))
        scal[1] = sbias[0] * (1.0f - tc[0]);        // coef
    }
}

// ---------------- Kernel B: embed (h fp32; q,k,m bf16; st, sbi) ----------------
__global__ __launch_bounds__(256) void embed_k(
    const float* __restrict__ nf, const float* __restrict__ tc,
    const float* __restrict__ w1, const float* __restrict__ b1,
    const float* __restrict__ w2, const float* __restrict__ b2,
    const float* __restrict__ wq, const float* __restrict__ bq,
    const float* __restrict__ wk, const float* __restrict__ bk,
    const float* __restrict__ wm, const float* __restrict__ bm,
    float* __restrict__ ws)
{
    const int w = threadIdx.x >> 6, lane = threadIdx.x & 63;
    const int row = blockIdx.x * 4 + w;
    __shared__ float ts[4][64], hs[4][64];
    const float qscale = ws[WS_SCAL + 0];
    const float coef   = ws[WS_SCAL + 1];
    const float f0 = nf[row * 3], f1 = nf[row * 3 + 1], f2 = nf[row * 3 + 2];
    const float t0 = tc[0], t1 = tc[1];
    float v = b1[lane];
    v = fmaf(f0, w1[lane], v);
    v = fmaf(f1, w1[64 + lane], v);
    v = fmaf(f2, w1[128 + lane], v);
    v = fmaf(t0, w1[192 + lane], v);
    v = fmaf(t1, w1[256 + lane], v);
    ts[w][lane] = fmaxf(v, 0.0f);
    __syncthreads();
    float hv = b2[lane];
    #pragma unroll 8
    for (int j = 0; j < 64; j++) hv = fmaf(ts[w][j], w2[j * 64 + lane], hv);
    hs[w][lane] = hv;
    ws[WS_H + row * 64 + lane] = hv;
    __syncthreads();
    float qv = bq[lane], kv = bk[lane], mv = bm[lane];
    #pragma unroll 4
    for (int j = 0; j < 64; j++) {
        const float hj = hs[w][j];
        qv = fmaf(hj, wq[j * 64 + lane], qv);
        kv = fmaf(hj, wk[j * 64 + lane], kv);
        mv = fmaf(hj, wm[j * 64 + lane], mv);
    }
    u16* wu = (u16*)ws;
    wu[WU_QB + row * 64 + lane] = f2bf(qv * qscale);
    wu[WU_KB + row * 64 + lane] = f2bf(kv);
    wu[WU_MB + row * 64 + lane] = f2bf(mv);
    if (lane == 0) {
        ws[WS_ST + row]  = f2;
        ws[WS_SBI + row] = f2 * coef;
    }
}

// ---------------- Kernel B2: transpose M (bf16) ----------------
__global__ __launch_bounds__(256) void transp_k(float* __restrict__ ws) {
    const u16* mb = (const u16*)ws + WU_MB;
    u16* mt = (u16*)ws + WU_MT;
    __shared__ __align__(16) u16 tile[64][72];
    const int i0 = blockIdx.x * 64;
    const int t = threadIdx.x;
    {
        const int r = t >> 2, cb = (t & 3) * 16;
        *(uint4*)&tile[r][cb]     = *(const uint4*)&mb[(size_t)(i0 + r) * 64 + cb];
        *(uint4*)&tile[r][cb + 8] = *(const uint4*)&mb[(size_t)(i0 + r) * 64 + cb + 8];
    }
    __syncthreads();
    const int c = t >> 2, rb = (t & 3) * 16;
    u16 tmp[16];
    #pragma unroll
    for (int i = 0; i < 16; i++) tmp[i] = tile[rb + i][c];
    *(uint4*)&mt[(size_t)c * N + i0 + rb]     = *(uint4*)&tmp[0];
    *(uint4*)&mt[(size_t)c * N + i0 + rb + 8] = *(uint4*)&tmp[8];
}

// ---------------- Kernel C: MFMA streaming attention, register-pipelined ----------------
// 256 threads (4 waves), 64x64 tiles, single-buffer LDS + 2-deep register pipeline.
__global__ __launch_bounds__(256, 3) void attn_k(const float* __restrict__ adj,
                                                 float* __restrict__ ws)
{
    const int rb = blockIdx.x, sp = blockIdx.y;
    const int i0 = rb * 64, j0 = sp * CPS;
    const int tid = threadIdx.x;
    const int lane = tid & 63;
    const int quad = lane >> 4, n16 = lane & 15;
    const int m0 = (tid >> 6) * 16;

    __shared__ __align__(16) u16 ks[64][72];   // 9.2 KB
    __shared__ __align__(16) u16 ms[64][72];   // 9.2 KB
    __shared__ __align__(16) u16 ps[64][72];   // 9.2 KB

    const u16* qb = (const u16*)ws + WU_QB;
    const u16* kb = (const u16*)ws + WU_KB;
    const u16* mt = (const u16*)ws + WU_MT;
    const float* st_g = ws + WS_ST;

    const int sr = tid >> 2, scb = (tid & 3) * 16;  // staging: 4 thr/row x 16 u16

    // ---- pipeline registers ----
    uint4 kmA[2][4];        // [slot][k0,k1,m0,m1] for tile x -> slot x&1
    float aaR[2][4][4];     // adj tile x -> slot x&1  [ct][reg]
    float stR[2][4];        // st  tile x -> slot x&1  [ct]

    // prologue: km(0) -> LDS, km(1) -> slot1, adj/st(0) -> slot0
    {
        const int jt = j0;
        uint4 k0 = *(const uint4*)&kb[(size_t)(jt + sr) * 64 + scb];
        uint4 k1 = *(const uint4*)&kb[(size_t)(jt + sr) * 64 + scb + 8];
        uint4 q0 = *(const uint4*)&mt[(size_t)sr * N + jt + scb];
        uint4 q1 = *(const uint4*)&mt[(size_t)sr * N + jt + scb + 8];
        #pragma unroll
        for (int reg = 0; reg < 4; reg++) {
            const size_t rowb = (size_t)(i0 + m0 + quad * 4 + reg) * N + jt + n16;
            #pragma unroll
            for (int ct = 0; ct < 4; ct++) aaR[0][ct][reg] = adj[rowb + ct * 16];
        }
        #pragma unroll
        for (int ct = 0; ct < 4; ct++) stR[0][ct] = st_g[jt + ct * 16 + n16];
        const int j1 = j0 + ((NTILE > 1) ? 64 : 0);
        kmA[1][0] = *(const uint4*)&kb[(size_t)(j1 + sr) * 64 + scb];
        kmA[1][1] = *(const uint4*)&kb[(size_t)(j1 + sr) * 64 + scb + 8];
        kmA[1][2] = *(const uint4*)&mt[(size_t)sr * N + j1 + scb];
        kmA[1][3] = *(const uint4*)&mt[(size_t)sr * N + j1 + scb + 8];
        *(uint4*)&ks[sr][scb]     = k0;
        *(uint4*)&ks[sr][scb + 8] = k1;
        *(uint4*)&ms[sr][scb]     = q0;
        *(uint4*)&ms[sr][scb + 8] = q1;
    }

    // Q fragments + sb row values straight from global
    const bf16x8 aq0 = *(const bf16x8*)&qb[(size_t)(i0 + m0 + n16) * 64 + quad * 8];
    const bf16x8 aq1 = *(const bf16x8*)&qb[(size_t)(i0 + m0 + n16) * 64 + 32 + quad * 8];
    float sbr[4];
    #pragma unroll
    for (int v = 0; v < 4; v++) sbr[v] = ws[WS_SBI + i0 + m0 + quad * 4 + v];

    f32x4 acc[4];
    #pragma unroll
    for (int i = 0; i < 4; i++) acc[i] = (f32x4){0.f, 0.f, 0.f, 0.f};
    float den[4] = {0.f, 0.f, 0.f, 0.f};

    __syncthreads();

    #pragma unroll 2
    for (int t = 0; t < NTILE; t++) {
        const int cur = t & 1, nxt = 1 - cur;
        // ---- issue future loads (clamped at the tail; redundant loads are L2-warm) ----
        {
            const int tk = (t + 2 < NTILE) ? t + 2 : NTILE - 1;
            const int jk = j0 + tk * 64;
            kmA[cur][0] = *(const uint4*)&kb[(size_t)(jk + sr) * 64 + scb];
            kmA[cur][1] = *(const uint4*)&kb[(size_t)(jk + sr) * 64 + scb + 8];
            kmA[cur][2] = *(const uint4*)&mt[(size_t)sr * N + jk + scb];
            kmA[cur][3] = *(const uint4*)&mt[(size_t)sr * N + jk + scb + 8];
            const int ta = (t + 1 < NTILE) ? t + 1 : NTILE - 1;
            const int ja = j0 + ta * 64;
            #pragma unroll
            for (int reg = 0; reg < 4; reg++) {
                const size_t rowb = (size_t)(i0 + m0 + quad * 4 + reg) * N + ja + n16;
                #pragma unroll
                for (int ct = 0; ct < 4; ct++) aaR[nxt][ct][reg] = adj[rowb + ct * 16];
            }
            #pragma unroll
            for (int ct = 0; ct < 4; ct++) stR[nxt][ct] = st_g[ja + ct * 16 + n16];
        }

        // ---- S = Q K^T (per-wave 16x64 strip) + epilogue + P -> LDS ----
        #pragma unroll
        for (int ct = 0; ct < 4; ct++) {
            const bf16x8 b0 = *(const bf16x8*)&ks[ct * 16 + n16][quad * 8];
            const bf16x8 b1 = *(const bf16x8*)&ks[ct * 16 + n16][32 + quad * 8];
            f32x4 s = {0.f, 0.f, 0.f, 0.f};
            s = __builtin_amdgcn_mfma_f32_16x16x32_bf16(aq0, b0, s, 0, 0, 0);
            s = __builtin_amdgcn_mfma_f32_16x16x32_bf16(aq1, b1, s, 0, 0, 0);
            const float stc = stR[cur][ct];
            #pragma unroll
            for (int reg = 0; reg < 4; reg++) {
                const float a = aaR[cur][ct][reg];
                const float sc = s[reg] + (a == 0.0f ? NEGV : a) + sbr[reg] * stc;
                const float p = __expf(sc);
                den[reg] += p;
                ps[m0 + quad * 4 + reg][ct * 16 + n16] = f2bf(p);
            }
        }
        __syncthreads();

        // ---- PV: acc += P(16x64) @ M(64x64) ----
        const bf16x8 ap0 = *(const bf16x8*)&ps[m0 + n16][quad * 8];
        const bf16x8 ap1 = *(const bf16x8*)&ps[m0 + n16][32 + quad * 8];
        #pragma unroll
        for (int nt = 0; nt < 4; nt++) {
            const bf16x8 b0 = *(const bf16x8*)&ms[nt * 16 + n16][quad * 8];
            const bf16x8 b1 = *(const bf16x8*)&ms[nt * 16 + n16][32 + quad * 8];
            acc[nt] = __builtin_amdgcn_mfma_f32_16x16x32_bf16(ap0, b0, acc[nt], 0, 0, 0);
            acc[nt] = __builtin_amdgcn_mfma_f32_16x16x32_bf16(ap1, b1, acc[nt], 0, 0, 0);
        }
        __syncthreads();

        // ---- write km(t+1) (loaded a full tile ago -> latency hidden) ----
        *(uint4*)&ks[sr][scb]     = kmA[nxt][0];
        *(uint4*)&ks[sr][scb + 8] = kmA[nxt][1];
        *(uint4*)&ms[sr][scb]     = kmA[nxt][2];
        *(uint4*)&ms[sr][scb + 8] = kmA[nxt][3];
        __syncthreads();
    }

    // write agg partials (C-layout rows) + reduced denominators
    float* aggp = ws + WS_AGG + (size_t)sp * N * 64;
    #pragma unroll
    for (int nt = 0; nt < 4; nt++) {
        #pragma unroll
        for (int reg = 0; reg < 4; reg++) {
            aggp[(size_t)(i0 + m0 + quad * 4 + reg) * 64 + nt * 16 + n16] = acc[nt][reg];
        }
    }
    #pragma unroll
    for (int reg = 0; reg < 4; reg++) {
        float d = den[reg];
        d += __shfl_xor(d, 1, 64);
        d += __shfl_xor(d, 2, 64);
        d += __shfl_xor(d, 4, 64);
        d += __shfl_xor(d, 8, 64);
        if (n16 == 0) ws[WS_DEN + sp * N + i0 + m0 + quad * 4 + reg] = d;
    }
}

// ---------------- Kernel D: combine + LayerNorm + final MLP ----------------
__global__ __launch_bounds__(256) void final_k(
    const float* __restrict__ sa, const float* __restrict__ ln_g,
    const float* __restrict__ ln_b,
    const float* __restrict__ wa1, const float* __restrict__ ba1,
    const float* __restrict__ wa2, const float* __restrict__ ba2,
    const float* __restrict__ ws, float* __restrict__ out)
{
    const int w = threadIdx.x >> 6, lane = threadIdx.x & 63;
    const int row = blockIdx.x * 4 + w;
    __shared__ float es[4][64], hs2[4][64];
    float a = 0.0f;
    #pragma unroll
    for (int sp = 0; sp < NSPLIT; sp++)
        a += ws[WS_AGG + (size_t)sp * N * 64 + (size_t)row * 64 + lane];
    float d = 0.0f;
    #pragma unroll
    for (int sp = 0; sp < NSPLIT; sp++) d += ws[WS_DEN + sp * N + row];
    const float z = ws[WS_H + row * 64 + lane] + a / d;
    float mu = z;
    for (int off = 32; off; off >>= 1) mu += __shfl_xor(mu, off, 64);
    mu *= (1.0f / 64.0f);
    const float zc = z - mu;
    float var = zc * zc;
    for (int off = 32; off; off >>= 1) var += __shfl_xor(var, off, 64);
    var *= (1.0f / 64.0f);
    const float emb = zc * rsqrtf(var + EPSV) * ln_g[lane] + ln_b[lane];
    es[w][lane] = emb;
    __syncthreads();
    const float sa0 = sa[row * 2], sa1 = sa[row * 2 + 1];
    float hv = ba1[lane];
    #pragma unroll 8
    for (int c = 0; c < 64; c++) hv = fmaf(es[w][c], wa1[c * 64 + lane], hv);
    hv = fmaf(sa0, wa1[64 * 64 + lane], hv);
    hv = fmaf(sa1, wa1[65 * 64 + lane], hv);
    hs2[w][lane] = fmaxf(hv, 0.0f);
    __syncthreads();
    if (lane < 3) {
        float o = ba2[lane];
        for (int u = 0; u < 64; u++) o = fmaf(hs2[w][u], wa2[u * 3 + lane], o);
        out[row * 3 + lane] = o;
    }
}

extern "C" void kernel_launch(void* const* d_in, const int* in_sizes, int n_in,
                              void* d_out, int out_size, void* d_ws, size_t ws_size,
                              hipStream_t stream)
{
    const float* nf  = (const float*)d_in[0];
    const float* adj = (const float*)d_in[1];
    const float* tc  = (const float*)d_in[2];
    const float* sa  = (const float*)d_in[3];
    const float* w1  = (const float*)d_in[4];
    const float* b1  = (const float*)d_in[5];
    const float* w2  = (const float*)d_in[6];
    const float* b2  = (const float*)d_in[7];
    const float* wq  = (const float*)d_in[8];
    const float* bq  = (const float*)d_in[9];
    const float* wk  = (const float*)d_in[10];
    const float* bk  = (const float*)d_in[11];
    const float* wg  = (const float*)d_in[12];
    const float* bg  = (const float*)d_in[13];
    const float* sb  = (const float*)d_in[14];
    const float* wm  = (const float*)d_in[15];
    const float* bm  = (const float*)d_in[16];
    const float* lng = (const float*)d_in[17];
    const float* lnb = (const float*)d_in[18];
    const float* wa1 = (const float*)d_in[19];
    const float* ba1 = (const float*)d_in[20];
    const float* wa2 = (const float*)d_in[21];
    const float* ba2 = (const float*)d_in[22];
    float* ws  = (float*)d_ws;
    float* out = (float*)d_out;

    prep_k<<<1, 64, 0, stream>>>(tc, wg, bg, sb, ws + WS_SCAL);
    embed_k<<<N / 4, 256, 0, stream>>>(nf, tc, w1, b1, w2, b2, wq, bq, wk, bk,
                                       wm, bm, ws);
    transp_k<<<N / 64, 256, 0, stream>>>(ws);
    attn_k<<<dim3(N / 64, NSPLIT), 256, 0, stream>>>(adj, ws);
    final_k<<<N / 4, 256, 0, stream>>>(sa, lng, lnb, wa1, ba1, wa2, ba2, ws, out);
}

// Round 5
// 491.562 us; speedup vs baseline: 1.1263x; 1.1263x over previous
//
#include <hip/hip_runtime.h>
#include <hip/hip_bf16.h>
#include <math.h>

#define N 8192
#define NEGV -1000000000.0f
#define EPSV 1e-05f
#define NSPLIT 8
#define CPS (N / NSPLIT)   // 1024 columns per split
#define NTILE (CPS / 64)   // 16 tiles (even -> manual 2x unroll is exact)

typedef short bf16x8 __attribute__((ext_vector_type(8)));
typedef float f32x4 __attribute__((ext_vector_type(4)));
typedef unsigned short u16;

// ---- float workspace layout ----
#define WS_SCAL 0
#define WS_H    64                        // N*64 fp32
#define WS_ST   (WS_H + N * 64)           // N
#define WS_SBI  (WS_ST + N)               // N
#define WS_DEN  (WS_SBI + N)              // NSPLIT*N
#define WS_AGG  (WS_DEN + NSPLIT * N)     // NSPLIT*N*64
#define WS_F_END (WS_AGG + NSPLIT * N * 64)
// ---- u16 (bf16) region, offsets in u16 units from (u16*)ws ----
#define WU_BASE (WS_F_END * 2)
#define WU_QB (WU_BASE)                   // N*64
#define WU_KB (WU_BASE + N * 64)          // N*64
#define WU_MB (WU_BASE + 2 * N * 64)      // N*64 (row-major, transposed later)
#define WU_MT (WU_BASE + 3 * N * 64)      // 64*N

static __device__ __forceinline__ u16 f2bf(float f) {
    __hip_bfloat16 h = __float2bfloat16(f);
    return *(u16*)&h;
}

// ---------------- Kernel A: scalar prep ----------------
__global__ void prep_k(const float* __restrict__ tc, const float* __restrict__ wg,
                       const float* __restrict__ bg, const float* __restrict__ sbias,
                       float* __restrict__ scal) {
    int j = threadIdx.x;  // 64 threads
    float v = tc[0] * wg[j] + tc[1] * wg[64 + j] + bg[j];
    float g = 1.0f / (1.0f + __expf(-v));
    for (int off = 32; off; off >>= 1) g += __shfl_xor(g, off, 64);
    if (j == 0) {
        scal[0] = 0.125f * (g * (1.0f / 64.0f));   // qscale (gate mean + 1/sqrt(64))
        scal[1] = sbias[0] * (1.0f - tc[0]);        // coef
    }
}

// ---------------- Kernel B: embed (h fp32; q,k,m bf16; st, sbi) ----------------
__global__ __launch_bounds__(256) void embed_k(
    const float* __restrict__ nf, const float* __restrict__ tc,
    const float* __restrict__ w1, const float* __restrict__ b1,
    const float* __restrict__ w2, const float* __restrict__ b2,
    const float* __restrict__ wq, const float* __restrict__ bq,
    const float* __restrict__ wk, const float* __restrict__ bk,
    const float* __restrict__ wm, const float* __restrict__ bm,
    float* __restrict__ ws)
{
    const int w = threadIdx.x >> 6, lane = threadIdx.x & 63;
    const int row = blockIdx.x * 4 + w;
    __shared__ float ts[4][64], hs[4][64];
    const float qscale = ws[WS_SCAL + 0];
    const float coef   = ws[WS_SCAL + 1];
    const float f0 = nf[row * 3], f1 = nf[row * 3 + 1], f2 = nf[row * 3 + 2];
    const float t0 = tc[0], t1 = tc[1];
    float v = b1[lane];
    v = fmaf(f0, w1[lane], v);
    v = fmaf(f1, w1[64 + lane], v);
    v = fmaf(f2, w1[128 + lane], v);
    v = fmaf(t0, w1[192 + lane], v);
    v = fmaf(t1, w1[256 + lane], v);
    ts[w][lane] = fmaxf(v, 0.0f);
    __syncthreads();
    float hv = b2[lane];
    #pragma unroll 8
    for (int j = 0; j < 64; j++) hv = fmaf(ts[w][j], w2[j * 64 + lane], hv);
    hs[w][lane] = hv;
    ws[WS_H + row * 64 + lane] = hv;
    __syncthreads();
    float qv = bq[lane], kv = bk[lane], mv = bm[lane];
    #pragma unroll 4
    for (int j = 0; j < 64; j++) {
        const float hj = hs[w][j];
        qv = fmaf(hj, wq[j * 64 + lane], qv);
        kv = fmaf(hj, wk[j * 64 + lane], kv);
        mv = fmaf(hj, wm[j * 64 + lane], mv);
    }
    u16* wu = (u16*)ws;
    wu[WU_QB + row * 64 + lane] = f2bf(qv * qscale);
    wu[WU_KB + row * 64 + lane] = f2bf(kv);
    wu[WU_MB + row * 64 + lane] = f2bf(mv);
    if (lane == 0) {
        ws[WS_ST + row]  = f2;
        ws[WS_SBI + row] = f2 * coef;
    }
}

// ---------------- Kernel B2: transpose M (bf16) ----------------
__global__ __launch_bounds__(256) void transp_k(float* __restrict__ ws) {
    const u16* mb = (const u16*)ws + WU_MB;
    u16* mt = (u16*)ws + WU_MT;
    __shared__ __align__(16) u16 tile[64][72];
    const int i0 = blockIdx.x * 64;
    const int t = threadIdx.x;
    {
        const int r = t >> 2, cb = (t & 3) * 16;
        *(uint4*)&tile[r][cb]     = *(const uint4*)&mb[(size_t)(i0 + r) * 64 + cb];
        *(uint4*)&tile[r][cb + 8] = *(const uint4*)&mb[(size_t)(i0 + r) * 64 + cb + 8];
    }
    __syncthreads();
    const int c = t >> 2, rb = (t & 3) * 16;
    u16 tmp[16];
    #pragma unroll
    for (int i = 0; i < 16; i++) tmp[i] = tile[rb + i][c];
    *(uint4*)&mt[(size_t)c * N + i0 + rb]     = *(uint4*)&tmp[0];
    *(uint4*)&mt[(size_t)c * N + i0 + rb + 8] = *(uint4*)&tmp[8];
}

// ---------------- Kernel C: MFMA streaming attention ----------------
// 4 waves, 64x64 tiles, double-buffered LDS K/Mt, adj prefetched one tile ahead
// into NAMED register sets via a textual macro (no dynamic array indexing ->
// no scratch spill; round-4's 293 MB WRITE_SIZE was spill traffic).
#define TILE_BODY(CUR, ADJ_RD, ST_RD, ADJ_WR, ST_WR)                          \
{                                                                             \
    const int jn = (jt + 64 < jend) ? (jt + 64) : jt;                         \
    _Pragma("unroll")                                                         \
    for (int reg = 0; reg < 4; reg++) {                                       \
        const size_t rowb = (size_t)(i0 + m0 + quad * 4 + reg) * N + jn + n16;\
        _Pragma("unroll")                                                     \
        for (int ct = 0; ct < 4; ct++) ADJ_WR[ct][reg] = adj[rowb + ct * 16]; \
    }                                                                         \
    _Pragma("unroll")                                                         \
    for (int ct = 0; ct < 4; ct++) ST_WR[ct] = st_g[jn + ct * 16 + n16];      \
    const uint4 kn0 = *(const uint4*)&kb[(size_t)(jn + sr) * 64 + scb];       \
    const uint4 kn1 = *(const uint4*)&kb[(size_t)(jn + sr) * 64 + scb + 8];   \
    const uint4 mn0 = *(const uint4*)&mt[(size_t)sr * N + jn + scb];          \
    const uint4 mn1 = *(const uint4*)&mt[(size_t)sr * N + jn + scb + 8];      \
    _Pragma("unroll")                                                         \
    for (int ct = 0; ct < 4; ct++) {                                          \
        const bf16x8 b0 = *(const bf16x8*)&ks[CUR][ct * 16 + n16][quad * 8];  \
        const bf16x8 b1 = *(const bf16x8*)&ks[CUR][ct * 16 + n16][32 + quad * 8]; \
        f32x4 s = {0.f, 0.f, 0.f, 0.f};                                       \
        s = __builtin_amdgcn_mfma_f32_16x16x32_bf16(aq0, b0, s, 0, 0, 0);     \
        s = __builtin_amdgcn_mfma_f32_16x16x32_bf16(aq1, b1, s, 0, 0, 0);     \
        const float stc = ST_RD[ct];                                          \
        _Pragma("unroll")                                                     \
        for (int reg = 0; reg < 4; reg++) {                                   \
            const float a = ADJ_RD[ct][reg];                                  \
            const float sc = s[reg] + (a == 0.0f ? NEGV : a) + sbr[reg] * stc;\
            const float p = __expf(sc);                                       \
            den[reg] += p;                                                    \
            ps[m0 + quad * 4 + reg][ct * 16 + n16] = f2bf(p);                 \
        }                                                                     \
    }                                                                         \
    __syncthreads();                                                          \
    {                                                                         \
        const bf16x8 ap0 = *(const bf16x8*)&ps[m0 + n16][quad * 8];           \
        const bf16x8 ap1 = *(const bf16x8*)&ps[m0 + n16][32 + quad * 8];      \
        _Pragma("unroll")                                                     \
        for (int nt = 0; nt < 4; nt++) {                                      \
            const bf16x8 b0 = *(const bf16x8*)&ms[CUR][nt * 16 + n16][quad * 8]; \
            const bf16x8 b1 = *(const bf16x8*)&ms[CUR][nt * 16 + n16][32 + quad * 8]; \
            acc[nt] = __builtin_amdgcn_mfma_f32_16x16x32_bf16(ap0, b0, acc[nt], 0, 0, 0); \
            acc[nt] = __builtin_amdgcn_mfma_f32_16x16x32_bf16(ap1, b1, acc[nt], 0, 0, 0); \
        }                                                                     \
    }                                                                         \
    *(uint4*)&ks[1 - (CUR)][sr][scb]     = kn0;                               \
    *(uint4*)&ks[1 - (CUR)][sr][scb + 8] = kn1;                               \
    *(uint4*)&ms[1 - (CUR)][sr][scb]     = mn0;                               \
    *(uint4*)&ms[1 - (CUR)][sr][scb + 8] = mn1;                               \
    __syncthreads();                                                          \
    jt += 64;                                                                 \
}

__global__ __launch_bounds__(256, 3) void attn_k(const float* __restrict__ adj,
                                                 float* __restrict__ ws)
{
    const int rb = blockIdx.x, sp = blockIdx.y;
    const int i0 = rb * 64, j0 = sp * CPS;
    const int jend = j0 + CPS;
    const int tid = threadIdx.x;
    const int lane = tid & 63;
    const int quad = lane >> 4, n16 = lane & 15;
    const int m0 = (tid >> 6) * 16;

    __shared__ __align__(16) u16 ks[2][64][72];   // 18.4 KB
    __shared__ __align__(16) u16 ms[2][64][72];   // 18.4 KB
    __shared__ __align__(16) u16 ps[64][76];      //  9.7 KB (pad 76: conflict-free writes)

    const u16* qb = (const u16*)ws + WU_QB;
    const u16* kb = (const u16*)ws + WU_KB;
    const u16* mt = (const u16*)ws + WU_MT;
    const float* st_g = ws + WS_ST;

    const int sr = tid >> 2, scb = (tid & 3) * 16;  // staging: 4 thr/row x 16 u16

    // named prefetch register sets (constant-indexed only -> stay in VGPRs)
    float adjA[4][4], adjB[4][4], stA[4], stB[4];

    // ---- prologue: adj/st(tile0) -> set A; K/M(tile0) -> LDS[0] ----
    #pragma unroll
    for (int reg = 0; reg < 4; reg++) {
        const size_t rowb = (size_t)(i0 + m0 + quad * 4 + reg) * N + j0 + n16;
        #pragma unroll
        for (int ct = 0; ct < 4; ct++) adjA[ct][reg] = adj[rowb + ct * 16];
    }
    #pragma unroll
    for (int ct = 0; ct < 4; ct++) stA[ct] = st_g[j0 + ct * 16 + n16];
    {
        const uint4 k0 = *(const uint4*)&kb[(size_t)(j0 + sr) * 64 + scb];
        const uint4 k1 = *(const uint4*)&kb[(size_t)(j0 + sr) * 64 + scb + 8];
        const uint4 q0 = *(const uint4*)&mt[(size_t)sr * N + j0 + scb];
        const uint4 q1 = *(const uint4*)&mt[(size_t)sr * N + j0 + scb + 8];
        *(uint4*)&ks[0][sr][scb]     = k0;
        *(uint4*)&ks[0][sr][scb + 8] = k1;
        *(uint4*)&ms[0][sr][scb]     = q0;
        *(uint4*)&ms[0][sr][scb + 8] = q1;
    }

    // Q fragments + per-row sb values from global
    const bf16x8 aq0 = *(const bf16x8*)&qb[(size_t)(i0 + m0 + n16) * 64 + quad * 8];
    const bf16x8 aq1 = *(const bf16x8*)&qb[(size_t)(i0 + m0 + n16) * 64 + 32 + quad * 8];
    float sbr[4];
    #pragma unroll
    for (int v = 0; v < 4; v++) sbr[v] = ws[WS_SBI + i0 + m0 + quad * 4 + v];

    f32x4 acc[4];
    #pragma unroll
    for (int i = 0; i < 4; i++) acc[i] = (f32x4){0.f, 0.f, 0.f, 0.f};
    float den[4] = {0.f, 0.f, 0.f, 0.f};

    __syncthreads();

    int jt = j0;
    for (int t = 0; t < NTILE; t += 2) {
        TILE_BODY(0, adjA, stA, adjB, stB)
        TILE_BODY(1, adjB, stB, adjA, stA)
    }

    // write agg partials (C-layout rows) + reduced denominators
    float* aggp = ws + WS_AGG + (size_t)sp * N * 64;
    #pragma unroll
    for (int nt = 0; nt < 4; nt++) {
        #pragma unroll
        for (int reg = 0; reg < 4; reg++) {
            aggp[(size_t)(i0 + m0 + quad * 4 + reg) * 64 + nt * 16 + n16] = acc[nt][reg];
        }
    }
    #pragma unroll
    for (int reg = 0; reg < 4; reg++) {
        float d = den[reg];
        d += __shfl_xor(d, 1, 64);
        d += __shfl_xor(d, 2, 64);
        d += __shfl_xor(d, 4, 64);
        d += __shfl_xor(d, 8, 64);
        if (n16 == 0) ws[WS_DEN + sp * N + i0 + m0 + quad * 4 + reg] = d;
    }
}

// ---------------- Kernel D: combine + LayerNorm + final MLP ----------------
__global__ __launch_bounds__(256) void final_k(
    const float* __restrict__ sa, const float* __restrict__ ln_g,
    const float* __restrict__ ln_b,
    const float* __restrict__ wa1, const float* __restrict__ ba1,
    const float* __restrict__ wa2, const float* __restrict__ ba2,
    const float* __restrict__ ws, float* __restrict__ out)
{
    const int w = threadIdx.x >> 6, lane = threadIdx.x & 63;
    const int row = blockIdx.x * 4 + w;
    __shared__ float es[4][64], hs2[4][64];
    float a = 0.0f;
    #pragma unroll
    for (int sp = 0; sp < NSPLIT; sp++)
        a += ws[WS_AGG + (size_t)sp * N * 64 + (size_t)row * 64 + lane];
    float d = 0.0f;
    #pragma unroll
    for (int sp = 0; sp < NSPLIT; sp++) d += ws[WS_DEN + sp * N + row];
    const float z = ws[WS_H + row * 64 + lane] + a / d;
    float mu = z;
    for (int off = 32; off; off >>= 1) mu += __shfl_xor(mu, off, 64);
    mu *= (1.0f / 64.0f);
    const float zc = z - mu;
    float var = zc * zc;
    for (int off = 32; off; off >>= 1) var += __shfl_xor(var, off, 64);
    var *= (1.0f / 64.0f);
    const float emb = zc * rsqrtf(var + EPSV) * ln_g[lane] + ln_b[lane];
    es[w][lane] = emb;
    __syncthreads();
    const float sa0 = sa[row * 2], sa1 = sa[row * 2 + 1];
    float hv = ba1[lane];
    #pragma unroll 8
    for (int c = 0; c < 64; c++) hv = fmaf(es[w][c], wa1[c * 64 + lane], hv);
    hv = fmaf(sa0, wa1[64 * 64 + lane], hv);
    hv = fmaf(sa1, wa1[65 * 64 + lane], hv);
    hs2[w][lane] = fmaxf(hv, 0.0f);
    __syncthreads();
    if (lane < 3) {
        float o = ba2[lane];
        for (int u = 0; u < 64; u++) o = fmaf(hs2[w][u], wa2[u * 3 + lane], o);
        out[row * 3 + lane] = o;
    }
}

extern "C" void kernel_launch(void* const* d_in, const int* in_sizes, int n_in,
                              void* d_out, int out_size, void* d_ws, size_t ws_size,
                              hipStream_t stream)
{
    const float* nf  = (const float*)d_in[0];
    const float* adj = (const float*)d_in[1];
    const float* tc  = (const float*)d_in[2];
    const float* sa  = (const float*)d_in[3];
    const float* w1  = (const float*)d_in[4];
    const float* b1  = (const float*)d_in[5];
    const float* w2  = (const float*)d_in[6];
    const float* b2  = (const float*)d_in[7];
    const float* wq  = (const float*)d_in[8];
    const float* bq  = (const float*)d_in[9];
    const float* wk  = (const float*)d_in[10];
    const float* bk  = (const float*)d_in[11];
    const float* wg  = (const float*)d_in[12];
    const float* bg  = (const float*)d_in[13];
    const float* sb  = (const float*)d_in[14];
    const float* wm  = (const float*)d_in[15];
    const float* bm  = (const float*)d_in[16];
    const float* lng = (const float*)d_in[17];
    const float* lnb = (const float*)d_in[18];
    const float* wa1 = (const float*)d_in[19];
    const float* ba1 = (const float*)d_in[20];
    const float* wa2 = (const float*)d_in[21];
    const float* ba2 = (const float*)d_in[22];
    float* ws  = (float*)d_ws;
    float* out = (float*)d_out;

    prep_k<<<1, 64, 0, stream>>>(tc, wg, bg, sb, ws + WS_SCAL);
    embed_k<<<N / 4, 256, 0, stream>>>(nf, tc, w1, b1, w2, b2, wq, bq, wk, bk,
                                       wm, bm, ws);
    transp_k<<<N / 64, 256, 0, stream>>>(ws);
    attn_k<<<dim3(N / 64, NSPLIT), 256, 0, stream>>>(adj, ws);
    final_k<<<N / 4, 256, 0, stream>>>(sa, lng, lnb, wa1, ba1, wa2, ba2, ws, out);
}